// Round 3
// baseline (121.973 us; speedup 1.0000x reference)
//
#include <hip/hip_runtime.h>

// fastmax linear attention (causal, p=1): chunked scan + bf16 MFMA matmuls.
// b=2, h=8, n=8192, d=32 -> bh=16, chunks of C=64 rows, 128 chunks per bh.
// TWO kernels (scan kernel deleted; the A->B launch boundary is the barrier):
//  1) chunk_agg: 2048 blocks, one per chunk.  Computes the chunk's own KV
//     outer-product sum (bf16 MFMA, fp32 acc) + fp32 ksum/vsum tails; writes
//     a 2.3KB aggregate: 1024 bf16 KV ([n][d1] MFMA staging layout) + 64 fp32.
//  2) output: each block sums the aggregates of the <=127 preceding chunks of
//     its bh in fp32 (8-wide unrolled predicated batches -> 8 loads in flight,
//     <=16 L2 roundtrips; per-bh aggregate set = 288KB, L2-resident), then the
//     usual MFMA numerator + fp32 denominator.  LDS 36.5KB -> 4 blocks/CU.

#define D      32
#define C      64
#define NCHUNK 128
#define BH     16
#define NBLK   (BH * NCHUNK)
#define AGGU   1152   // ushorts per chunk aggregate: 1024 bf16 KV + 64 fp32 tail

typedef __attribute__((ext_vector_type(8))) short bf16x8;
typedef __attribute__((ext_vector_type(4))) float f32x4;
typedef __attribute__((ext_vector_type(4))) unsigned short u16x4;

__device__ __forceinline__ unsigned short f2bf(float x) {
  union { float f; unsigned u; } c; c.f = x;
  unsigned r = (c.u + 0x7FFFu + ((c.u >> 16) & 1u)) >> 16;   // RNE
  return (unsigned short)r;
}
__device__ __forceinline__ float bf2f(unsigned short u) {
  union { unsigned u; float f; } c; c.u = ((unsigned)u) << 16;
  return c.f;
}
// MFMA output col n = original col (n<16 ? 2n : 2(n-16)+1); element with
// original col e stages at row n(e) = (e&1) ? 16+(e>>1) : (e>>1)
__device__ __forceinline__ int permcol(int e) {
  return (e & 1) ? (16 + (e >> 1)) : (e >> 1);
}

// ---------------------------------------------------------------------------
// Kernel 1: per-chunk KV aggregate.  grid = NBLK = 2048, no loop, no scan.
// ---------------------------------------------------------------------------
__global__ __launch_bounds__(256) void chunk_agg_kernel(
    const float* __restrict__ k, const float* __restrict__ v,
    unsigned short* __restrict__ agg) {
  int blk = blockIdx.x;                  // bh*NCHUNK + c
  const float4* kp = (const float4*)k + (size_t)blk * 512;
  const float4* vp = (const float4*)v + (size_t)blk * 512;

  __shared__ __align__(16) unsigned short kT[D * 72];   // [e][j]
  __shared__ __align__(16) unsigned short vT[D * 72];   // [e][j]
  __shared__ __align__(16) float4 psK[256];             // per-thread col partials
  __shared__ __align__(16) float4 psV[256];

  int t  = threadIdx.x;
  int j0 = t >> 3;
  int cb = (t & 7) * 4;
  int lane = t & 63, w = t >> 6;
  int m16 = lane & 15, quad = lane >> 4;
  int mb = w >> 1, nb = w & 1;
  int d1b = 16 * mb + quad * 4;
  int d2  = 16 * nb + m16;
  int n   = permcol(d2);                 // staging row for this thread's col

  float4 kA = kp[t], kB = kp[t + 256];
  float4 vA = vp[t], vB = vp[t + 256];

  {
    const float* ka = &kA.x; const float* kb = &kB.x;
    const float* va = &vA.x; const float* vb = &vB.x;
#pragma unroll
    for (int cc = 0; cc < 4; ++cc) {
      kT[(cb + cc) * 72 + j0]      = f2bf(ka[cc]);
      kT[(cb + cc) * 72 + j0 + 32] = f2bf(kb[cc]);
      vT[(cb + cc) * 72 + j0]      = f2bf(va[cc]);
      vT[(cb + cc) * 72 + j0 + 32] = f2bf(vb[cc]);
    }
    psK[t] = make_float4(kA.x + kB.x, kA.y + kB.y, kA.z + kB.z, kA.w + kB.w);
    psV[t] = make_float4(vA.x + vB.x, vA.y + vB.y, vA.z + vB.z, vA.w + vB.w);
  }
  __syncthreads();

  // KV = K^T.V for this chunk (4 16x16 tiles across 4 waves)
  f32x4 acc = {0.f, 0.f, 0.f, 0.f};
#pragma unroll
  for (int kb2 = 0; kb2 < 2; ++kb2) {
    bf16x8 a = *(const bf16x8*)&kT[(16 * mb + m16) * 72 + kb2 * 32 + quad * 8];
    bf16x8 b = *(const bf16x8*)&vT[(16 * nb + m16) * 72 + kb2 * 32 + quad * 8];
    acc = __builtin_amdgcn_mfma_f32_16x16x32_bf16(a, b, acc, 0, 0, 0);
  }

  unsigned short* ap = agg + (size_t)blk * AGGU;
  *(u16x4*)&ap[n * 32 + d1b] =
      (u16x4){f2bf(acc[0]), f2bf(acc[1]), f2bf(acc[2]), f2bf(acc[3])};
  if (t < 64) {
    int ee = t & 31;
    const float* ps = (t < 32) ? (const float*)psK : (const float*)psV;
    float csum = 0.f;
#pragma unroll
    for (int m = 0; m < 32; ++m) csum += ps[ee + 32 * m];
    ((float*)(ap + 1024))[t] = csum;    // fp32 tail (den-critical ksum!)
  }
}

// ---------------------------------------------------------------------------
// Kernel 2: MFMA output kernel.  grid = NBLK, 256 threads (4 waves).
// Inline exclusive prefix: batched in-flight reads of preceding aggregates.
// ---------------------------------------------------------------------------
__global__ __launch_bounds__(256, 4) void output_kernel(
    const float* __restrict__ q, const float* __restrict__ k,
    const float* __restrict__ v, const unsigned short* __restrict__ agg,
    float* __restrict__ out) {
  int blk = blockIdx.x;
  int c   = blk & 127;
  int bh  = blk >> 7;
  size_t off = (size_t)blk * (C * D);
  const float4* qp4 = (const float4*)q + (size_t)blk * 512;
  const float4* kp4 = (const float4*)k + (size_t)blk * 512;
  const float4* vp4 = (const float4*)v + (size_t)blk * 512;
  const unsigned short* abh = agg + (size_t)(bh * NCHUNK) * AGGU;

  // union region: {qbf[64][40] | kbf[64][40]} during staging+part1;
  // q_s[64][36] fp32 (written in part2, read in part3) afterwards.
  __shared__ __align__(16) char uA[10240];
  unsigned short* qbf = (unsigned short*)uA;            // [i][dd]
  unsigned short* kbf = (unsigned short*)(uA + 5120);   // [j][dd]
  float* q_s = (float*)uA;                              // [i][dd] fp32, part2+
  __shared__ __align__(16) unsigned short vTbf[D * 72];   // [n][j] permuted cols
  __shared__ __align__(16) unsigned short kvTbf[D * 40];  // [n][dd] permuted cols
  __shared__ __align__(16) unsigned short Tbf[C * 72];    // [i][j]
  __shared__ __align__(16) float kc_s[C * 36];            // fp32 k -> cumsum+kpre
  __shared__ __align__(16) float gtot[8 * 32];
  __shared__ __align__(16) float pre_s[64];               // [0:32)=ksum, [32:64)=vsum prefix
  __shared__ __align__(16) float invdiv_s[C];

  int t  = threadIdx.x;
  int j0 = t >> 3;
  int cb = (t & 7) * 4;

  // ---- issue all global loads first ---------------------------------------
  float4 qA = qp4[t], qB = qp4[t + 256];
  float4 kA = kp4[t], kB = kp4[t + 256];
  float4 vA = vp4[t], vB = vp4[t + 256];

  // ---- inline exclusive prefix over preceding chunk aggregates ------------
  // 8 independent loads in flight per round; predication is wave-uniform.
  float s0 = 0.f, s1 = 0.f, s2 = 0.f, s3 = 0.f;   // this thread's 4 KV elems
  float tf = 0.f;                                  // tail elem (t<64)
  for (int p0 = 0; p0 < c; p0 += 8) {
    uint2 r[8]; float tl[8];
#pragma unroll
    for (int u = 0; u < 8; ++u) {
      int p = p0 + u;
      const unsigned short* apx = abh + (size_t)(p < c ? p : 0) * AGGU;
      r[u] = *(const uint2*)&apx[4 * t];
      if (t < 64) tl[u] = ((const float*)(apx + 1024))[t];
    }
#pragma unroll
    for (int u = 0; u < 8; ++u) {
      if (p0 + u < c) {
        s0 += bf2f((unsigned short)(r[u].x & 0xffff));
        s1 += bf2f((unsigned short)(r[u].x >> 16));
        s2 += bf2f((unsigned short)(r[u].y & 0xffff));
        s3 += bf2f((unsigned short)(r[u].y >> 16));
        if (t < 64) tf += tl[u];
      }
    }
  }

  // zero Tbf while loads are in flight (masked region must read 0)
  for (int z = t; z < (C * 72) / 8; z += 256)
    ((uint4*)Tbf)[z] = make_uint4(0, 0, 0, 0);

  // ---- convert + stage (q_s deferred to part2: union with qbf/kbf) --------
  *(float4*)&kc_s[j0 * 36 + cb]        = kA;
  *(float4*)&kc_s[(j0 + 32) * 36 + cb] = kB;
  *(u16x4*)&qbf[j0 * 40 + cb] =
      (u16x4){f2bf(qA.x), f2bf(qA.y), f2bf(qA.z), f2bf(qA.w)};
  *(u16x4*)&qbf[(j0 + 32) * 40 + cb] =
      (u16x4){f2bf(qB.x), f2bf(qB.y), f2bf(qB.z), f2bf(qB.w)};
  *(u16x4*)&kbf[j0 * 40 + cb] =
      (u16x4){f2bf(kA.x), f2bf(kA.y), f2bf(kA.z), f2bf(kA.w)};
  *(u16x4*)&kbf[(j0 + 32) * 40 + cb] =
      (u16x4){f2bf(kB.x), f2bf(kB.y), f2bf(kB.z), f2bf(kB.w)};
  {
    const float* va = &vA.x; const float* vb = &vB.x;
#pragma unroll
    for (int cc = 0; cc < 4; ++cc) {
      int n = permcol(cb + cc);
      vTbf[n * 72 + j0]      = f2bf(va[cc]);
      vTbf[n * 72 + j0 + 32] = f2bf(vb[cc]);
    }
  }
  // KV prefix: fp32 accumulated -> bf16, direct layout copy ([n][d1] linear)
  *(u16x4*)&kvTbf[(t >> 3) * 40 + (t & 7) * 4] =
      (u16x4){f2bf(s0), f2bf(s1), f2bf(s2), f2bf(s3)};
  if (t < 64) pre_s[t] = tf;
  __syncthreads();

  int lane = t & 63, w = t >> 6;
  int m16 = lane & 15, quad = lane >> 4;

  // ---- part 1: S tiles -> Tbf;  scan phase a ------------------------------
  const bf16x8 aQ = *(const bf16x8*)&qbf[(16 * w + m16) * 40 + quad * 8];
  for (int jb = 0; jb <= w; ++jb) {
    bf16x8 bK = *(const bf16x8*)&kbf[(16 * jb + m16) * 40 + quad * 8];
    f32x4 cS = {0.f, 0.f, 0.f, 0.f};
    cS = __builtin_amdgcn_mfma_f32_16x16x32_bf16(aQ, bK, cS, 0, 0, 0);
    int jcol = 16 * jb + m16;
#pragma unroll
    for (int reg = 0; reg < 4; ++reg) {
      int i = 16 * w + quad * 4 + reg;
      float tv = (jcol <= i) ? (1.f + cS[reg]) : 0.f;
      Tbf[i * 72 + jcol] = f2bf(tv);
    }
  }
  int rg = t >> 5;                     // row-group 0..7
  int e  = t & 31;
  float vals[8];
  {
    float run = 0.f;
#pragma unroll
    for (int r = 0; r < 8; ++r) {
      vals[r] = kc_s[(rg * 8 + r) * 36 + e];
      run += vals[r];
    }
    gtot[rg * 32 + e] = run;
  }
  __syncthreads();                     // qbf/kbf dead past this point

  // ---- part 2: apply group offsets + kpre, write k-cumsum; stage q_s ------
  {
    float offv = pre_s[e];             // ksum prefix
    for (int g2 = 0; g2 < rg; ++g2) offv += gtot[g2 * 32 + e];
    float cacc = offv;
#pragma unroll
    for (int r = 0; r < 8; ++r) {
      cacc += vals[r];
      kc_s[(rg * 8 + r) * 36 + e] = cacc;   // kpre + cumsum_local(k)
    }
  }
  *(float4*)&q_s[j0 * 36 + cb]        = qA;   // overwrites dead qbf/kbf
  *(float4*)&q_s[(j0 + 32) * 36 + cb] = qB;
  __syncthreads();

  // ---- part 3: fp32 den (wave 0) + O MFMAs (all waves) --------------------
  if (t < 64) {
    int i = t;
    float dp = 0.f;
#pragma unroll
    for (int d4 = 0; d4 < 8; ++d4) {
      float4 qv = *(const float4*)&q_s[i * 36 + 4 * d4];
      float4 kc = *(const float4*)&kc_s[i * 36 + 4 * d4];
      dp += qv.x * kc.x + qv.y * kc.y + qv.z * kc.z + qv.w * kc.w;
    }
    invdiv_s[i] = 1.f / ((float)(c * C + i + 1) + dp);
  }
  f32x4 o0 = {0.f, 0.f, 0.f, 0.f}, o1 = {0.f, 0.f, 0.f, 0.f};
  {
    bf16x8 b0 = *(const bf16x8*)&kvTbf[(m16)      * 40 + quad * 8];
    bf16x8 b1 = *(const bf16x8*)&kvTbf[(16 + m16) * 40 + quad * 8];
    o0 = __builtin_amdgcn_mfma_f32_16x16x32_bf16(aQ, b0, o0, 0, 0, 0);
    o1 = __builtin_amdgcn_mfma_f32_16x16x32_bf16(aQ, b1, o1, 0, 0, 0);
  }
  int kbcnt = (w >= 2) ? 2 : 1;        // T zero past column 16w+15
  for (int kb2 = 0; kb2 < kbcnt; ++kb2) {
    bf16x8 aT = *(const bf16x8*)&Tbf[(16 * w + m16) * 72 + kb2 * 32 + quad * 8];
    bf16x8 b0 = *(const bf16x8*)&vTbf[(m16)      * 72 + kb2 * 32 + quad * 8];
    bf16x8 b1 = *(const bf16x8*)&vTbf[(16 + m16) * 72 + kb2 * 32 + quad * 8];
    o0 = __builtin_amdgcn_mfma_f32_16x16x32_bf16(aT, b0, o0, 0, 0, 0);
    o1 = __builtin_amdgcn_mfma_f32_16x16x32_bf16(aT, b1, o1, 0, 0, 0);
  }
  __syncthreads();

  // ---- epilogue: columns 2*m16, 2*m16+1 -> float2 stores ------------------
  int e0 = 2 * m16;
#pragma unroll
  for (int reg = 0; reg < 4; ++reg) {
    int i = 16 * w + quad * 4 + reg;
    float id = invdiv_s[i];
    float2 o;
    o.x = (pre_s[32 + e0]     + o0[reg]) * id;   // vsum prefix
    o.y = (pre_s[32 + e0 + 1] + o1[reg]) * id;
    *(float2*)&out[off + (size_t)i * D + e0] = o;
  }
}

// ---------------------------------------------------------------------------
extern "C" void kernel_launch(void* const* d_in, const int* in_sizes, int n_in,
                              void* d_out, int out_size, void* d_ws, size_t ws_size,
                              hipStream_t stream) {
  const float* q = (const float*)d_in[0];
  const float* k = (const float*)d_in[1];
  const float* v = (const float*)d_in[2];
  float* out = (float*)d_out;
  unsigned short* agg = (unsigned short*)d_ws;   // NBLK * AGGU ushorts = 4.7 MB

  chunk_agg_kernel<<<NBLK, 256, 0, stream>>>(k, v, agg);
  output_kernel<<<NBLK, 256, 0, stream>>>(q, k, v, agg, out);
}

// Round 4
// 106.511 us; speedup vs baseline: 1.1452x; 1.1452x over previous
//
#include <hip/hip_runtime.h>

// fastmax linear attention (causal, p=1): chunked scan + bf16 MFMA matmuls.
// b=2, h=8, n=8192, d=32 -> bh=16, chunks of C=64 rows, 128 chunks per bh,
// 16 groups of 8 chunks per bh.  THREE kernels, hierarchical prefix:
//  1) chunk_agg: 2048 blocks, one per chunk.  Chunk's own KV outer-product
//     sum (bf16 MFMA, fp32 acc) + fp32 ksum/vsum tails -> 2.3KB aggregate
//     (1024 bf16 KV in [n][d1] MFMA staging layout + 64 fp32 tail).
//  2) group_scan: 256 blocks = one per (bh, group-of-8).  Reads the 8 chunk
//     aggs (all loads in flight), writes each chunk's within-group EXCLUSIVE
//     prefix (pref) + the group's INCLUSIVE total (gtot).  No serial memory
//     chain: the depth-8 scan lives entirely in registers.
//  3) output: full prefix = pref[chunk] + sum of <=15 preceding gtot vectors
//     (<=2 predicated 8-wide batched rounds -> <=16 loads in flight).
//     Lookback traffic 2048 x ~20KB ~= 40MB (was 300MB -> L3-BW-bound).
//     Then the usual MFMA numerator + fp32 denominator.  LDS 36.5KB.

#define D      32
#define C      64
#define NCHUNK 128
#define GSIZE  8
#define NGROUP 16
#define BH     16
#define NBLK   (BH * NCHUNK)
#define AGGU   1152   // ushorts per aggregate: 1024 bf16 KV + 64 fp32 tail

typedef __attribute__((ext_vector_type(8))) short bf16x8;
typedef __attribute__((ext_vector_type(4))) float f32x4;
typedef __attribute__((ext_vector_type(4))) unsigned short u16x4;

__device__ __forceinline__ unsigned short f2bf(float x) {
  union { float f; unsigned u; } c; c.f = x;
  unsigned r = (c.u + 0x7FFFu + ((c.u >> 16) & 1u)) >> 16;   // RNE
  return (unsigned short)r;
}
__device__ __forceinline__ float bf2f(unsigned short u) {
  union { unsigned u; float f; } c; c.u = ((unsigned)u) << 16;
  return c.f;
}
// MFMA output col n = original col (n<16 ? 2n : 2(n-16)+1); element with
// original col e stages at row n(e) = (e&1) ? 16+(e>>1) : (e>>1)
__device__ __forceinline__ int permcol(int e) {
  return (e & 1) ? (16 + (e >> 1)) : (e >> 1);
}

// ---------------------------------------------------------------------------
// Kernel 1: per-chunk KV aggregate.  grid = NBLK = 2048, no loop, no scan.
// ---------------------------------------------------------------------------
__global__ __launch_bounds__(256) void chunk_agg_kernel(
    const float* __restrict__ k, const float* __restrict__ v,
    unsigned short* __restrict__ agg) {
  int blk = blockIdx.x;                  // bh*NCHUNK + c
  const float4* kp = (const float4*)k + (size_t)blk * 512;
  const float4* vp = (const float4*)v + (size_t)blk * 512;

  __shared__ __align__(16) unsigned short kT[D * 72];   // [e][j]
  __shared__ __align__(16) unsigned short vT[D * 72];   // [e][j]
  __shared__ __align__(16) float4 psK[256];             // per-thread col partials
  __shared__ __align__(16) float4 psV[256];

  int t  = threadIdx.x;
  int j0 = t >> 3;
  int cb = (t & 7) * 4;
  int lane = t & 63, w = t >> 6;
  int m16 = lane & 15, quad = lane >> 4;
  int mb = w >> 1, nb = w & 1;
  int d1b = 16 * mb + quad * 4;
  int d2  = 16 * nb + m16;
  int n   = permcol(d2);                 // staging row for this thread's col

  float4 kA = kp[t], kB = kp[t + 256];
  float4 vA = vp[t], vB = vp[t + 256];

  {
    const float* ka = &kA.x; const float* kb = &kB.x;
    const float* va = &vA.x; const float* vb = &vB.x;
#pragma unroll
    for (int cc = 0; cc < 4; ++cc) {
      kT[(cb + cc) * 72 + j0]      = f2bf(ka[cc]);
      kT[(cb + cc) * 72 + j0 + 32] = f2bf(kb[cc]);
      vT[(cb + cc) * 72 + j0]      = f2bf(va[cc]);
      vT[(cb + cc) * 72 + j0 + 32] = f2bf(vb[cc]);
    }
    psK[t] = make_float4(kA.x + kB.x, kA.y + kB.y, kA.z + kB.z, kA.w + kB.w);
    psV[t] = make_float4(vA.x + vB.x, vA.y + vB.y, vA.z + vB.z, vA.w + vB.w);
  }
  __syncthreads();

  // KV = K^T.V for this chunk (4 16x16 tiles across 4 waves)
  f32x4 acc = {0.f, 0.f, 0.f, 0.f};
#pragma unroll
  for (int kb2 = 0; kb2 < 2; ++kb2) {
    bf16x8 a = *(const bf16x8*)&kT[(16 * mb + m16) * 72 + kb2 * 32 + quad * 8];
    bf16x8 b = *(const bf16x8*)&vT[(16 * nb + m16) * 72 + kb2 * 32 + quad * 8];
    acc = __builtin_amdgcn_mfma_f32_16x16x32_bf16(a, b, acc, 0, 0, 0);
  }

  unsigned short* ap = agg + (size_t)blk * AGGU;
  *(u16x4*)&ap[n * 32 + d1b] =
      (u16x4){f2bf(acc[0]), f2bf(acc[1]), f2bf(acc[2]), f2bf(acc[3])};
  if (t < 64) {
    int ee = t & 31;
    const float* ps = (t < 32) ? (const float*)psK : (const float*)psV;
    float csum = 0.f;
#pragma unroll
    for (int m = 0; m < 32; ++m) csum += ps[ee + 32 * m];
    ((float*)(ap + 1024))[t] = csum;    // fp32 tail (den-critical ksum!)
  }
}

// ---------------------------------------------------------------------------
// Kernel 2: per-group register scan.  grid = BH*NGROUP = 256 blocks.
// Reads 8 chunk aggs (loads all in flight), writes 8 within-group exclusive
// prefixes (pref, separate buffer -> no load/store aliasing) + 1 inclusive
// group total (gtot).
// ---------------------------------------------------------------------------
__global__ __launch_bounds__(256) void group_scan_kernel(
    const unsigned short* __restrict__ agg, unsigned short* __restrict__ pref,
    unsigned short* __restrict__ gtot) {
  int blk = blockIdx.x;                  // bh*NGROUP + g
  int t   = threadIdx.x;
  const unsigned short* a0 = agg + (size_t)blk * GSIZE * AGGU;
  unsigned short* p0 = pref + (size_t)blk * GSIZE * AGGU;

  uint2 r[GSIZE]; float tl[GSIZE];
#pragma unroll
  for (int u = 0; u < GSIZE; ++u) {
    r[u] = *(const uint2*)&a0[(size_t)u * AGGU + 4 * t];
    if (t < 64) tl[u] = ((const float*)(a0 + (size_t)u * AGGU + 1024))[t];
  }
  float s0 = 0.f, s1 = 0.f, s2 = 0.f, s3 = 0.f, st = 0.f;
#pragma unroll
  for (int u = 0; u < GSIZE; ++u) {
    *(u16x4*)&p0[(size_t)u * AGGU + 4 * t] =
        (u16x4){f2bf(s0), f2bf(s1), f2bf(s2), f2bf(s3)};
    if (t < 64) ((float*)(p0 + (size_t)u * AGGU + 1024))[t] = st;
    s0 += bf2f((unsigned short)(r[u].x & 0xffff));
    s1 += bf2f((unsigned short)(r[u].x >> 16));
    s2 += bf2f((unsigned short)(r[u].y & 0xffff));
    s3 += bf2f((unsigned short)(r[u].y >> 16));
    if (t < 64) st += tl[u];
  }
  unsigned short* gt = gtot + (size_t)blk * AGGU;
  *(u16x4*)&gt[4 * t] = (u16x4){f2bf(s0), f2bf(s1), f2bf(s2), f2bf(s3)};
  if (t < 64) ((float*)(gt + 1024))[t] = st;
}

// ---------------------------------------------------------------------------
// Kernel 3: MFMA output kernel.  grid = NBLK, 256 threads (4 waves).
// Prefix = pref[chunk] + sum of <=15 preceding group totals (<=2 rounds of
// 8 predicated in-flight loads).
// ---------------------------------------------------------------------------
__global__ __launch_bounds__(256, 4) void output_kernel(
    const float* __restrict__ q, const float* __restrict__ k,
    const float* __restrict__ v, const unsigned short* __restrict__ pref,
    const unsigned short* __restrict__ gtot, float* __restrict__ out) {
  int blk = blockIdx.x;
  int c   = blk & 127;
  int bh  = blk >> 7;
  int g   = c >> 3;                      // group index, 0..15
  size_t off = (size_t)blk * (C * D);
  const float4* qp4 = (const float4*)q + (size_t)blk * 512;
  const float4* kp4 = (const float4*)k + (size_t)blk * 512;
  const float4* vp4 = (const float4*)v + (size_t)blk * 512;
  const unsigned short* prf = pref + (size_t)blk * AGGU;
  const unsigned short* gtb = gtot + (size_t)(bh * NGROUP) * AGGU;

  // union region: {qbf[64][40] | kbf[64][40]} during staging+part1;
  // q_s[64][36] fp32 (written in part2, read in part3) afterwards.
  __shared__ __align__(16) char uA[10240];
  unsigned short* qbf = (unsigned short*)uA;            // [i][dd]
  unsigned short* kbf = (unsigned short*)(uA + 5120);   // [j][dd]
  float* q_s = (float*)uA;                              // [i][dd] fp32, part2+
  __shared__ __align__(16) unsigned short vTbf[D * 72];   // [n][j] permuted cols
  __shared__ __align__(16) unsigned short kvTbf[D * 40];  // [n][dd] permuted cols
  __shared__ __align__(16) unsigned short Tbf[C * 72];    // [i][j]
  __shared__ __align__(16) float kc_s[C * 36];            // fp32 k -> cumsum+kpre
  __shared__ __align__(16) float gtot_s[8 * 32];
  __shared__ __align__(16) float pre_s[64];               // [0:32)=ksum, [32:64)=vsum prefix
  __shared__ __align__(16) float invdiv_s[C];

  int t  = threadIdx.x;
  int j0 = t >> 3;
  int cb = (t & 7) * 4;

  // ---- issue all global loads first ---------------------------------------
  float4 qA = qp4[t], qB = qp4[t + 256];
  float4 kA = kp4[t], kB = kp4[t + 256];
  float4 vA = vp4[t], vB = vp4[t + 256];

  // ---- hierarchical exclusive prefix: pref + <=15 group totals ------------
  uint2 rp = *(const uint2*)&prf[4 * t];
  float tlp = 0.f;
  if (t < 64) tlp = ((const float*)(prf + 1024))[t];
  float s0 = bf2f((unsigned short)(rp.x & 0xffff));
  float s1 = bf2f((unsigned short)(rp.x >> 16));
  float s2 = bf2f((unsigned short)(rp.y & 0xffff));
  float s3 = bf2f((unsigned short)(rp.y >> 16));
  float tf = tlp;
  for (int p0 = 0; p0 < g; p0 += 8) {    // <=2 rounds, 8 loads in flight each
    uint2 r[8]; float tl[8];
#pragma unroll
    for (int u = 0; u < 8; ++u) {
      int p = p0 + u;
      const unsigned short* gp = gtb + (size_t)(p < g ? p : 0) * AGGU;
      r[u] = *(const uint2*)&gp[4 * t];
      if (t < 64) tl[u] = ((const float*)(gp + 1024))[t];
    }
#pragma unroll
    for (int u = 0; u < 8; ++u) {
      if (p0 + u < g) {
        s0 += bf2f((unsigned short)(r[u].x & 0xffff));
        s1 += bf2f((unsigned short)(r[u].x >> 16));
        s2 += bf2f((unsigned short)(r[u].y & 0xffff));
        s3 += bf2f((unsigned short)(r[u].y >> 16));
        if (t < 64) tf += tl[u];
      }
    }
  }

  // zero Tbf while loads are in flight (masked region must read 0)
  for (int z = t; z < (C * 72) / 8; z += 256)
    ((uint4*)Tbf)[z] = make_uint4(0, 0, 0, 0);

  // ---- convert + stage (q_s deferred to part2: union with qbf/kbf) --------
  *(float4*)&kc_s[j0 * 36 + cb]        = kA;
  *(float4*)&kc_s[(j0 + 32) * 36 + cb] = kB;
  *(u16x4*)&qbf[j0 * 40 + cb] =
      (u16x4){f2bf(qA.x), f2bf(qA.y), f2bf(qA.z), f2bf(qA.w)};
  *(u16x4*)&qbf[(j0 + 32) * 40 + cb] =
      (u16x4){f2bf(qB.x), f2bf(qB.y), f2bf(qB.z), f2bf(qB.w)};
  *(u16x4*)&kbf[j0 * 40 + cb] =
      (u16x4){f2bf(kA.x), f2bf(kA.y), f2bf(kA.z), f2bf(kA.w)};
  *(u16x4*)&kbf[(j0 + 32) * 40 + cb] =
      (u16x4){f2bf(kB.x), f2bf(kB.y), f2bf(kB.z), f2bf(kB.w)};
  {
    const float* va = &vA.x; const float* vb = &vB.x;
#pragma unroll
    for (int cc = 0; cc < 4; ++cc) {
      int n = permcol(cb + cc);
      vTbf[n * 72 + j0]      = f2bf(va[cc]);
      vTbf[n * 72 + j0 + 32] = f2bf(vb[cc]);
    }
  }
  // KV prefix: fp32 accumulated -> bf16, direct layout copy ([n][d1] linear)
  *(u16x4*)&kvTbf[(t >> 3) * 40 + (t & 7) * 4] =
      (u16x4){f2bf(s0), f2bf(s1), f2bf(s2), f2bf(s3)};
  if (t < 64) pre_s[t] = tf;
  __syncthreads();

  int lane = t & 63, w = t >> 6;
  int m16 = lane & 15, quad = lane >> 4;

  // ---- part 1: S tiles -> Tbf;  scan phase a ------------------------------
  const bf16x8 aQ = *(const bf16x8*)&qbf[(16 * w + m16) * 40 + quad * 8];
  for (int jb = 0; jb <= w; ++jb) {
    bf16x8 bK = *(const bf16x8*)&kbf[(16 * jb + m16) * 40 + quad * 8];
    f32x4 cS = {0.f, 0.f, 0.f, 0.f};
    cS = __builtin_amdgcn_mfma_f32_16x16x32_bf16(aQ, bK, cS, 0, 0, 0);
    int jcol = 16 * jb + m16;
#pragma unroll
    for (int reg = 0; reg < 4; ++reg) {
      int i = 16 * w + quad * 4 + reg;
      float tv = (jcol <= i) ? (1.f + cS[reg]) : 0.f;
      Tbf[i * 72 + jcol] = f2bf(tv);
    }
  }
  int rg = t >> 5;                     // row-group 0..7
  int e  = t & 31;
  float vals[8];
  {
    float run = 0.f;
#pragma unroll
    for (int r = 0; r < 8; ++r) {
      vals[r] = kc_s[(rg * 8 + r) * 36 + e];
      run += vals[r];
    }
    gtot_s[rg * 32 + e] = run;
  }
  __syncthreads();                     // qbf/kbf dead past this point

  // ---- part 2: apply group offsets + kpre, write k-cumsum; stage q_s ------
  {
    float offv = pre_s[e];             // ksum prefix
    for (int g2 = 0; g2 < rg; ++g2) offv += gtot_s[g2 * 32 + e];
    float cacc = offv;
#pragma unroll
    for (int r = 0; r < 8; ++r) {
      cacc += vals[r];
      kc_s[(rg * 8 + r) * 36 + e] = cacc;   // kpre + cumsum_local(k)
    }
  }
  *(float4*)&q_s[j0 * 36 + cb]        = qA;   // overwrites dead qbf/kbf
  *(float4*)&q_s[(j0 + 32) * 36 + cb] = qB;
  __syncthreads();

  // ---- part 3: fp32 den (wave 0) + O MFMAs (all waves) --------------------
  if (t < 64) {
    int i = t;
    float dp = 0.f;
#pragma unroll
    for (int d4 = 0; d4 < 8; ++d4) {
      float4 qv = *(const float4*)&q_s[i * 36 + 4 * d4];
      float4 kc = *(const float4*)&kc_s[i * 36 + 4 * d4];
      dp += qv.x * kc.x + qv.y * kc.y + qv.z * kc.z + qv.w * kc.w;
    }
    invdiv_s[i] = 1.f / ((float)(c * C + i + 1) + dp);
  }
  f32x4 o0 = {0.f, 0.f, 0.f, 0.f}, o1 = {0.f, 0.f, 0.f, 0.f};
  {
    bf16x8 b0 = *(const bf16x8*)&kvTbf[(m16)      * 40 + quad * 8];
    bf16x8 b1 = *(const bf16x8*)&kvTbf[(16 + m16) * 40 + quad * 8];
    o0 = __builtin_amdgcn_mfma_f32_16x16x32_bf16(aQ, b0, o0, 0, 0, 0);
    o1 = __builtin_amdgcn_mfma_f32_16x16x32_bf16(aQ, b1, o1, 0, 0, 0);
  }
  int kbcnt = (w >= 2) ? 2 : 1;        // T zero past column 16w+15
  for (int kb2 = 0; kb2 < kbcnt; ++kb2) {
    bf16x8 aT = *(const bf16x8*)&Tbf[(16 * w + m16) * 72 + kb2 * 32 + quad * 8];
    bf16x8 b0 = *(const bf16x8*)&vTbf[(m16)      * 72 + kb2 * 32 + quad * 8];
    bf16x8 b1 = *(const bf16x8*)&vTbf[(16 + m16) * 72 + kb2 * 32 + quad * 8];
    o0 = __builtin_amdgcn_mfma_f32_16x16x32_bf16(aT, b0, o0, 0, 0, 0);
    o1 = __builtin_amdgcn_mfma_f32_16x16x32_bf16(aT, b1, o1, 0, 0, 0);
  }
  __syncthreads();

  // ---- epilogue: columns 2*m16, 2*m16+1 -> float2 stores ------------------
  int e0 = 2 * m16;
#pragma unroll
  for (int reg = 0; reg < 4; ++reg) {
    int i = 16 * w + quad * 4 + reg;
    float id = invdiv_s[i];
    float2 o;
    o.x = (pre_s[32 + e0]     + o0[reg]) * id;   // vsum prefix
    o.y = (pre_s[32 + e0 + 1] + o1[reg]) * id;
    *(float2*)&out[off + (size_t)i * D + e0] = o;
  }
}

// ---------------------------------------------------------------------------
extern "C" void kernel_launch(void* const* d_in, const int* in_sizes, int n_in,
                              void* d_out, int out_size, void* d_ws, size_t ws_size,
                              hipStream_t stream) {
  const float* q = (const float*)d_in[0];
  const float* k = (const float*)d_in[1];
  const float* v = (const float*)d_in[2];
  float* out = (float*)d_out;
  unsigned short* agg  = (unsigned short*)d_ws;                  // 4.7 MB
  unsigned short* pref = agg  + (size_t)NBLK * AGGU;             // 4.7 MB
  unsigned short* gtot = pref + (size_t)NBLK * AGGU;             // 0.6 MB

  chunk_agg_kernel<<<NBLK, 256, 0, stream>>>(k, v, agg);
  group_scan_kernel<<<BH * NGROUP, 256, 0, stream>>>(agg, pref, gtot);
  output_kernel<<<NBLK, 256, 0, stream>>>(q, k, v, pref, gtot, out);
}